// Round 1
// baseline (69.856 us; speedup 1.0000x reference)
//
#include <hip/hip_runtime.h>

#define NROWS 4096
#define NCOLS 10000
#define NLAT  64
#define NCOLG 2500   /* NCOLS / 4 */
#define TPB   256

// Kernel 1: streaming pass over X. Each thread owns 4 consecutive columns
// (float4 = 16B/lane, coalesced), each block-row-chunk accumulates partial
// column sums + sums-of-squares into workspace (fixed order -> deterministic).
__global__ void colsum_partials(const float* __restrict__ X,
                                float* __restrict__ ps,
                                float* __restrict__ ps2,
                                int rowsPerChunk) {
    int jg = blockIdx.x * TPB + threadIdx.x;          // column group (4 cols)
    if (jg >= NCOLG) return;
    int r0 = blockIdx.y * rowsPerChunk;
    int r1 = r0 + rowsPerChunk;
    if (r1 > NROWS) r1 = NROWS;

    float s0 = 0.f, s1 = 0.f, s2 = 0.f, s3 = 0.f;
    float q0 = 0.f, q1 = 0.f, q2 = 0.f, q3 = 0.f;
    const float* base = X + (size_t)r0 * NCOLS + (size_t)jg * 4;
    for (int r = r0; r < r1; ++r) {
        float4 v = *reinterpret_cast<const float4*>(base);
        base += NCOLS;
        s0 += v.x; s1 += v.y; s2 += v.z; s3 += v.w;
        q0 += v.x * v.x; q1 += v.y * v.y; q2 += v.z * v.z; q3 += v.w * v.w;
    }
    size_t o = (size_t)blockIdx.y * NCOLS + (size_t)jg * 4;
    *reinterpret_cast<float4*>(ps  + o) = make_float4(s0, s1, s2, s3);
    *reinterpret_cast<float4*>(ps2 + o) = make_float4(q0, q1, q2, q3);
}

// Kernel 2: fold row-chunk partials -> s[j], s2[j]; compute w2[j]=sum_f V[j,f]^2
// and per-block partial of q = sum_j s2[j]*w2[j].
__global__ void reduce_and_q(const float* __restrict__ ps,
                             const float* __restrict__ ps2,
                             const float* __restrict__ V,
                             float* __restrict__ s_out,
                             float* __restrict__ qpart,
                             int rc) {
    int j = blockIdx.x * TPB + threadIdx.x;
    float q = 0.f;
    if (j < NCOLS) {
        float s = 0.f, s2 = 0.f;
        for (int c = 0; c < rc; ++c) {
            s  += ps [(size_t)c * NCOLS + j];
            s2 += ps2[(size_t)c * NCOLS + j];
        }
        s_out[j] = s;
        float w2 = 0.f;
        const float4* vp = reinterpret_cast<const float4*>(V + (size_t)j * NLAT);
        #pragma unroll
        for (int k = 0; k < NLAT / 4; ++k) {
            float4 v = vp[k];
            w2 += v.x * v.x + v.y * v.y + v.z * v.z + v.w * v.w;
        }
        q = s2 * w2;
    }
    // block reduction (4 waves of 64)
    for (int o = 32; o > 0; o >>= 1) q += __shfl_down(q, o, 64);
    __shared__ float tmp[TPB / 64];
    int lane = threadIdx.x & 63, w = threadIdx.x >> 6;
    if (lane == 0) tmp[w] = q;
    __syncthreads();
    if (threadIdx.x == 0) qpart[blockIdx.x] = tmp[0] + tmp[1] + tmp[2] + tmp[3];
}

// Kernel 3: t[f] = sum_j V[j,f] * s[j]. One block per latent dim f.
__global__ void matvec_t(const float* __restrict__ V,
                         const float* __restrict__ s,
                         float* __restrict__ t) {
    int f = blockIdx.x;
    float acc = 0.f;
    for (int j = threadIdx.x; j < NCOLS; j += TPB)
        acc += V[(size_t)j * NLAT + f] * s[j];
    for (int o = 32; o > 0; o >>= 1) acc += __shfl_down(acc, o, 64);
    __shared__ float tmp[TPB / 64];
    int lane = threadIdx.x & 63, w = threadIdx.x >> 6;
    if (lane == 0) tmp[w] = acc;
    __syncthreads();
    if (threadIdx.x == 0) t[f] = tmp[0] + tmp[1] + tmp[2] + tmp[3];
}

// Kernel 4: out = 0.5 * (sum_f t[f]^2 - q). One wave.
__global__ void finalize(const float* __restrict__ t,
                         const float* __restrict__ qpart,
                         int nq, float* __restrict__ out) {
    float v = t[threadIdx.x];
    float tt = v * v;
    for (int o = 32; o > 0; o >>= 1) tt += __shfl_down(tt, o, 64);
    if (threadIdx.x == 0) {
        float q = 0.f;
        for (int b = 0; b < nq; ++b) q += qpart[b];
        out[0] = 0.5f * (tt - q);
    }
}

extern "C" void kernel_launch(void* const* d_in, const int* in_sizes, int n_in,
                              void* d_out, int out_size, void* d_ws, size_t ws_size,
                              hipStream_t stream) {
    const float* X = (const float*)d_in[0];   // [4096, 10000] f32
    const float* V = (const float*)d_in[1];   // [10000, 64]  f32
    float* out = (float*)d_out;               // scalar f32

    // Pick row-chunk count RC to fit workspace: need RC*2*NCOLS + ~10.2K floats.
    size_t floats = ws_size / sizeof(float);
    long rc = 1;
    const size_t overhead = NCOLS + NLAT + 64;
    if (floats > overhead + 2 * NCOLS)
        rc = (long)((floats - overhead) / (2 * (size_t)NCOLS));
    if (rc > 64) rc = 64;
    if (rc < 1) rc = 1;
    int rowsPerChunk = (NROWS + (int)rc - 1) / (int)rc;
    int nrc = (NROWS + rowsPerChunk - 1) / rowsPerChunk;  // actual chunks used

    float* ps    = (float*)d_ws;                    // [nrc][NCOLS]
    float* ps2   = ps  + (size_t)nrc * NCOLS;       // [nrc][NCOLS]
    float* s_out = ps2 + (size_t)nrc * NCOLS;       // [NCOLS]
    float* t     = s_out + NCOLS;                   // [NLAT]
    float* qp    = t + NLAT;                        // [nqb]

    int nqb = (NCOLS + TPB - 1) / TPB;  // 40

    colsum_partials<<<dim3((NCOLG + TPB - 1) / TPB, nrc), TPB, 0, stream>>>(
        X, ps, ps2, rowsPerChunk);
    reduce_and_q<<<nqb, TPB, 0, stream>>>(ps, ps2, V, s_out, qp, nrc);
    matvec_t<<<NLAT, TPB, 0, stream>>>(V, s_out, t);
    finalize<<<1, 64, 0, stream>>>(t, qp, nqb, out);
}